// Round 4
// baseline (210.874 us; speedup 1.0000x reference)
//
#include <hip/hip_runtime.h>

#define N_CTX 2048
#define DHEAD 64
#define SCALE_F 0.125f
#define EPS_F 1e-6f
#define KT 64
#define NITER (N_CTX / KT)
#define QBLK 256           // q per block: 8 waves x 32 q

typedef __attribute__((ext_vector_type(8))) short short8;
typedef __attribute__((ext_vector_type(4))) short short4v;
typedef __attribute__((ext_vector_type(4))) float float4v;
typedef __attribute__((ext_vector_type(2))) unsigned uint2v;
typedef __attribute__((ext_vector_type(4))) unsigned uint4v;

// ---- bf16 pack: HW cvt_pk on device, parse-only fallback for host pass ----
#if defined(__HIP_DEVICE_COMPILE__) && __has_builtin(__builtin_amdgcn_cvt_pk_bf16_f32)
typedef __attribute__((ext_vector_type(2))) __bf16 bf16x2;
__device__ __forceinline__ unsigned pack2(float a, float b) {
    union { bf16x2 v; unsigned u; } x;
    x.v = __builtin_amdgcn_cvt_pk_bf16_f32(a, b);
    return x.u;
}
#else
__device__ __forceinline__ unsigned bf1(float f) {
    union { float f; unsigned u; } x; x.f = f;
    return (x.u + 0x7FFFu + ((x.u >> 16) & 1u)) >> 16;
}
__device__ __forceinline__ unsigned pack2(float a, float b) {
    return bf1(a) | (bf1(b) << 16);
}
#endif

// ---- K=16 bf16 MFMA (A,B = 4 bf16/lane; C/D = float4) ----
#if defined(__HIP_DEVICE_COMPILE__)
  #if __has_builtin(__builtin_amdgcn_mfma_f32_16x16x16bf16_1k)
    #define MFMA16(a, b, c) __builtin_amdgcn_mfma_f32_16x16x16bf16_1k(a, b, c, 0, 0, 0)
  #elif __has_builtin(__builtin_amdgcn_mfma_f32_16x16x16_bf16_1k)
    #define MFMA16(a, b, c) __builtin_amdgcn_mfma_f32_16x16x16_bf16_1k(a, b, c, 0, 0, 0)
  #else
    __device__ __forceinline__ float4v mfma16_asm(short4v a, short4v b, float4v c) {
        asm volatile("v_mfma_f32_16x16x16_bf16 %0, %1, %2, %0"
                     : "+v"(c) : "v"(a), "v"(b));
        return c;
    }
    #define MFMA16(a, b, c) mfma16_asm(a, b, c)
  #endif
#else
  #define MFMA16(a, b, c) (c)   /* host pass: parse-only, never executed */
#endif

// Layouts (gfx950, m89-verified):
//  mfma 16x16x32: A[m=lane&15][k=8q+j], B[k=8q+j][n=lane&15], C[row=4q+r][col=lane&15]
//  mfma 16x16x16: A[m=lane&15][k=4q+j], B[k=4q+j][n=lane&15]  (q = lane>>4)
// S^T = K*Q^T: its C-layout rows kv=4q+r equal the K=16 A-frag k=4q+j ->
// square in registers, pack, feed PV with zero data movement.

__global__ __launch_bounds__(512, 4)
void powsm_attn(const float* __restrict__ qg, const float* __restrict__ kg,
                const float* __restrict__ vg, float* __restrict__ og)
{
    __shared__ short Ks[64][72];   // K tile row-major bf16
    __shared__ short Vt[64][68];   // V transposed Vt[d][kv]
    __shared__ float Dn[8][32];    // per-wave denominator exchange

    // XCD swizzle: xcd = linear%8 (heuristic). Give each XCD a contiguous
    // band of 8 bh so its blocks share K/V in L2.
    const int i     = blockIdx.x;
    const int bh    = (i & 7) * 8 + ((i >> 3) & 7);
    const int qtile = i >> 6;

    const int tid  = threadIdx.x;
    const int wave = tid >> 6;
    const int lane = tid & 63;
    const int qd   = lane >> 4;    // quad 0..3
    const int c    = lane & 15;

    const size_t base = (size_t)bh * N_CTX * DHEAD;
    const float* qp = qg + base;
    const float* kp = kg + base;
    const float* vp = vg + base;
    float*       op = og + base;

    const int qw0 = qtile * QBLK + wave * 32;

    // ---- hoist Q B-frags (16x16x32), SCALE folded in ----
    short8 Qf[2][2];
    #pragma unroll
    for (int qt = 0; qt < 2; ++qt) {
        #pragma unroll
        for (int ks = 0; ks < 2; ++ks) {
            const float* src = qp + (size_t)(qw0 + qt*16 + c) * DHEAD + ks*32 + qd*8;
            float4v a = *(const float4v*)(src);
            float4v b = *(const float4v*)(src + 4);
            uint4v u;
            u[0] = pack2(a[0]*SCALE_F, a[1]*SCALE_F);
            u[1] = pack2(a[2]*SCALE_F, a[3]*SCALE_F);
            u[2] = pack2(b[0]*SCALE_F, b[1]*SCALE_F);
            u[3] = pack2(b[2]*SCALE_F, b[3]*SCALE_F);
            union { uint4v u; short8 s; } cv; cv.u = u;
            Qf[qt][ks] = cv.s;
        }
    }

    float4v Oacc[2][4];            // [qt][nt]
    #pragma unroll
    for (int qt = 0; qt < 2; ++qt)
        #pragma unroll
        for (int nt = 0; nt < 4; ++nt)
            Oacc[qt][nt] = (float4v){0.f, 0.f, 0.f, 0.f};
    float4v dacc[2];
    dacc[0] = (float4v){0.f, 0.f, 0.f, 0.f};
    dacc[1] = (float4v){0.f, 0.f, 0.f, 0.f};

    // ---- staging split: waves 0-3 stage K, waves 4-7 stage V ----
    const bool isV = (wave >= 4);
    const int  st  = tid & 255;    // 0..255 within the half
    const int  sr  = st >> 4;      // row group 0..15
    const int  sc  = st & 15;      // col group 0..15

    float4v pf[4];
    if (!isV) {
        #pragma unroll
        for (int u = 0; u < 4; ++u)
            pf[u] = *(const float4v*)(kp + (size_t)(sr + u*16) * DHEAD + sc*4);
    } else {
        #pragma unroll
        for (int j = 0; j < 4; ++j)
            pf[j] = *(const float4v*)(vp + (size_t)(4*sr + j) * DHEAD + sc*4);
    }

    #pragma unroll 1
    for (int kvi = 0; kvi < NITER; ++kvi) {
        __syncthreads();   // previous iter's frag reads complete

        if (!isV) {        // K tile, row-major
            #pragma unroll
            for (int u = 0; u < 4; ++u) {
                uint2v w; w[0] = pack2(pf[u][0], pf[u][1]); w[1] = pack2(pf[u][2], pf[u][3]);
                *(uint2v*)&Ks[sr + u*16][sc*4] = w;
            }
        } else {           // V tile, transposed 4x4 blocks
            #pragma unroll
            for (int kk = 0; kk < 4; ++kk) {
                uint2v w; w[0] = pack2(pf[0][kk], pf[1][kk]); w[1] = pack2(pf[2][kk], pf[3][kk]);
                *(uint2v*)&Vt[4*sc + kk][4*sr] = w;
            }
        }
        __syncthreads();

        // ---- prefetch next tile (overlaps compute) ----
        if (kvi + 1 < NITER) {
            const float* src = (isV ? vp : kp) + (size_t)(kvi + 1) * KT * DHEAD;
            if (!isV) {
                #pragma unroll
                for (int u = 0; u < 4; ++u)
                    pf[u] = *(const float4v*)(src + (size_t)(sr + u*16) * DHEAD + sc*4);
            } else {
                #pragma unroll
                for (int j = 0; j < 4; ++j)
                    pf[j] = *(const float4v*)(src + (size_t)(4*sr + j) * DHEAD + sc*4);
            }
        }

        // ---- per 16-kv chunk: S^T -> square -> PV (all in registers) ----
        #pragma unroll
        for (int mt = 0; mt < 4; ++mt) {
            float4v s[2];
            s[0] = (float4v){0.f, 0.f, 0.f, 0.f};
            s[1] = (float4v){0.f, 0.f, 0.f, 0.f};
            #pragma unroll
            for (int ks = 0; ks < 2; ++ks) {
                short8 af = *(const short8*)&Ks[mt*16 + c][ks*32 + qd*8];
                #pragma unroll
                for (int qt = 0; qt < 2; ++qt)
                    s[qt] = __builtin_amdgcn_mfma_f32_16x16x32_bf16(af, Qf[qt][ks], s[qt], 0, 0, 0);
            }
            short4v pa[2];
            #pragma unroll
            for (int qt = 0; qt < 2; ++qt) {
                float4v p = s[qt] * s[qt];   // v_pk_mul_f32
                dacc[qt] += p;               // v_pk_add_f32
                union { uint2v u; short4v s; } cv;
                cv.u[0] = pack2(p[0], p[1]); cv.u[1] = pack2(p[2], p[3]);
                pa[qt] = cv.s;
            }
            #pragma unroll
            for (int nt = 0; nt < 4; ++nt) {
                short4v bf = *(const short4v*)&Vt[nt*16 + c][mt*16 + qd*4];
                #pragma unroll
                for (int qt = 0; qt < 2; ++qt)
                    Oacc[qt][nt] = MFMA16(pa[qt], bf, Oacc[qt][nt]);
            }
        }
    }

    // ---- denominator: full sum per q via cross-quad reduce ----
    #pragma unroll
    for (int qt = 0; qt < 2; ++qt) {
        float d = (dacc[qt][0] + dacc[qt][1]) + (dacc[qt][2] + dacc[qt][3]);
        d += __shfl_xor(d, 16);
        d += __shfl_xor(d, 32);
        if (qd == 0) Dn[wave][qt*16 + c] = d;
    }
    __syncthreads();

    // ---- epilogue ----
    #pragma unroll
    for (int qt = 0; qt < 2; ++qt) {
        #pragma unroll
        for (int r = 0; r < 4; ++r) {
            float inv = 1.0f / (Dn[wave][qt*16 + qd*4 + r] + EPS_F);
            float* dst = op + (size_t)(qw0 + qt*16 + qd*4 + r) * DHEAD + c;
            #pragma unroll
            for (int nt = 0; nt < 4; ++nt)
                dst[nt*16] = Oacc[qt][nt][r] * inv;
        }
    }
}

extern "C" void kernel_launch(void* const* d_in, const int* in_sizes, int n_in,
                              void* d_out, int out_size, void* d_ws, size_t ws_size,
                              hipStream_t stream) {
    const float* q = (const float*)d_in[0];
    const float* k = (const float*)d_in[1];
    const float* v = (const float*)d_in[2];
    float* out = (float*)d_out;
    dim3 grid((N_CTX / QBLK) * 64, 1, 1);   // 512 blocks, swizzled in-kernel
    powsm_attn<<<grid, dim3(512, 1, 1), 0, stream>>>(q, k, v, out);
}